// Round 9
// baseline (777.721 us; speedup 1.0000x reference)
//
#include <hip/hip_runtime.h>
#include <math.h>

#define D_DIM 4096
#define NWG 1280  // 5 WGs/CU x 256 CUs; persistent grid-stride

typedef float v2f __attribute__((ext_vector_type(2)));

// ---- packed-f32 butterfly primitives (VOP3P) ----
__device__ __forceinline__ v2f bfly0(v2f a) {
    v2f d;
    asm("v_pk_add_f32 %0, %1, %2 op_sel:[0,1] op_sel_hi:[0,1] neg_hi:[0,1]"
        : "=v"(d) : "v"(a), "v"(a));
    return d;
}
__device__ __forceinline__ v2f pkadd(v2f a, v2f b) {
    v2f d; asm("v_pk_add_f32 %0, %1, %2" : "=v"(d) : "v"(a), "v"(b)); return d;
}
__device__ __forceinline__ v2f pksub(v2f a, v2f b) {
    v2f d; asm("v_pk_add_f32 %0, %1, %2 neg_lo:[0,1] neg_hi:[0,1]" : "=v"(d) : "v"(a), "v"(b)); return d;
}
__device__ __forceinline__ v2f pkmul(v2f a, v2f b) {
    v2f d; asm("v_pk_mul_f32 %0, %1, %2" : "=v"(d) : "v"(a), "v"(b)); return d;
}

// In-register FWHT over 6 bits: 64 values as 32 packed v2f.
__device__ __forceinline__ void radix64(v2f w[32]) {
#pragma unroll
    for (int p = 0; p < 32; ++p) w[p] = bfly0(w[p]);
#pragma unroll
    for (int s = 0; s < 5; ++s) {
        const int d = 1 << s;
#pragma unroll
        for (int p = 0; p < 32; ++p) {
            if (!(p & d)) {
                const v2f a = w[p];
                const v2f b = w[p + d];
                w[p]     = pkadd(a, b);
                w[p + d] = pksub(a, b);
            }
        }
    }
}

// u_perm[l*64 + m] = u[e]/64, e = (l>>2)*256 + m*4 + (l&3)  (B-layout).
__global__ void compute_u_kernel(const float* __restrict__ g_mu,
                                 const float* __restrict__ g_rho,
                                 const float* __restrict__ eps,
                                 float* __restrict__ u_perm) {
    const int j = blockIdx.x * blockDim.x + threadIdx.x;
    if (j < D_DIM) {
        const int e = ((j >> 8) << 8) | ((j & 63) << 2) | ((j >> 6) & 3);
        const float r = g_rho[e];
        const float sp = (r > 20.0f) ? r : log1pf(expf(r));
        u_perm[j] = (g_mu[e] + sp * eps[e]) * 0.015625f;
    }
}

// Persistent kernel: 1280 WGs x 4 waves; each wave owns an 8 KB LDS slice and
// processes rows wave_id, wave_id+5120, ... independently. NO workgroup
// barriers: all LDS hazards are intra-wave (DS ops execute in order per wave;
// compiler inserts lgkmcnt waits for the write->read dependencies).
// 32 KB LDS/WG -> 5 WGs/CU -> 20 waves/CU.
// 64x64 lane<->reg transpose in two 8 KB half-stages (verified round 8):
//   stage v in [32,64): all lanes write; lanes l>=32 read their row of 64;
//   then stage v in [0,32) for lanes l<32. Reads land in a fresh array so the
//   not-yet-staged half of the source regs survives.
__global__ __launch_bounds__(256, 5) void whvi_kernel(const float* __restrict__ x,
                                                      const float* __restrict__ s1,
                                                      const float* __restrict__ s2,
                                                      const float* __restrict__ u_perm,
                                                      float* __restrict__ out,
                                                      int nrows) {
    __shared__ float lds_all[4 * 2048];  // 8 KB per wave
    const int l = threadIdx.x & 63;
    const int wv = threadIdx.x >> 6;
    float* __restrict__ lds = &lds_all[wv << 11];
    const int l4 = l << 2;
    const int L4 = (l & 15) << 2;

    const int wave_id = (blockIdx.x << 2) + wv;
    const int wstride = NWG << 2;

    for (int row = wave_id; row < nrows; row += wstride) {
        const float* __restrict__ xr = x + (size_t)row * D_DIM;

        v2f w[32];

        // ---- phase A: coalesced b128 loads of x and s2, FWHT bits {0,1,8..11} ----
#pragma unroll
        for (int k = 0; k < 16; ++k) {
            const int off = (k << 8) + l4;  // e = 256k + 4l + q
            const float4 xv = *reinterpret_cast<const float4*>(xr + off);
            const float4 sv = *reinterpret_cast<const float4*>(s2 + off);
            w[2 * k]     = pkmul((v2f){xv.x, xv.y}, (v2f){sv.x, sv.y});
            w[2 * k + 1] = pkmul((v2f){xv.z, xv.w}, (v2f){sv.z, sv.w});
        }
        radix64(w);

        v2f nw[32];

        // ---- T1, half 0: stage v in [32,64); readers are lanes l >= 32 ----
#pragma unroll
        for (int v = 32; v < 64; ++v)
            lds[((v & 31) << 6) + (l ^ ((v & 15) << 2))] = (v & 1) ? w[v >> 1].y : w[v >> 1].x;
        if (l >= 32) {
#pragma unroll
            for (int k = 0; k < 16; ++k) {
                const float4 f = *reinterpret_cast<const float4*>(&lds[((l & 31) << 6) + ((k << 2) ^ L4)]);
                nw[2 * k]     = (v2f){f.x, f.y};
                nw[2 * k + 1] = (v2f){f.z, f.w};
            }
        }

        // ---- T1, half 1: stage v in [0,32); readers are lanes l < 32 ----
        // (in-order DS pipe: these writes cannot bypass the reads above)
#pragma unroll
        for (int v = 0; v < 32; ++v)
            lds[((v & 31) << 6) + (l ^ ((v & 15) << 2))] = (v & 1) ? w[v >> 1].y : w[v >> 1].x;
        if (l < 32) {
#pragma unroll
            for (int k = 0; k < 16; ++k) {
                const float4 f = *reinterpret_cast<const float4*>(&lds[((l & 31) << 6) + ((k << 2) ^ L4)]);
                nw[2 * k]     = (v2f){f.x, f.y};
                nw[2 * k + 1] = (v2f){f.z, f.w};
            }
        }

        // ---- phase B: FWHT bits {2..7}, * u, FWHT bits {2..7} ----
        radix64(nw);
#pragma unroll
        for (int k = 0; k < 16; ++k) {
            const float4 uv = *reinterpret_cast<const float4*>(u_perm + (l << 6) + (k << 2));
            nw[2 * k]     = pkmul(nw[2 * k],     (v2f){uv.x, uv.y});
            nw[2 * k + 1] = pkmul(nw[2 * k + 1], (v2f){uv.z, uv.w});
        }
        radix64(nw);

        // ---- T2, half 0: stage m in [32,64); readers l >= 32 ----
#pragma unroll
        for (int m = 32; m < 64; ++m)
            lds[((m & 31) << 6) + (l ^ ((m & 15) << 2))] = (m & 1) ? nw[m >> 1].y : nw[m >> 1].x;
        if (l >= 32) {
#pragma unroll
            for (int k = 0; k < 16; ++k) {
                const float4 f = *reinterpret_cast<const float4*>(&lds[((l & 31) << 6) + ((k << 2) ^ L4)]);
                w[2 * k]     = (v2f){f.x, f.y};
                w[2 * k + 1] = (v2f){f.z, f.w};
            }
        }

        // ---- T2, half 1: stage m in [0,32); readers l < 32 ----
#pragma unroll
        for (int m = 0; m < 32; ++m)
            lds[((m & 31) << 6) + (l ^ ((m & 15) << 2))] = (m & 1) ? nw[m >> 1].y : nw[m >> 1].x;
        if (l < 32) {
#pragma unroll
            for (int k = 0; k < 16; ++k) {
                const float4 f = *reinterpret_cast<const float4*>(&lds[((l & 31) << 6) + ((k << 2) ^ L4)]);
                w[2 * k]     = (v2f){f.x, f.y};
                w[2 * k + 1] = (v2f){f.z, f.w};
            }
        }

        // ---- phase A': FWHT bits {0,1,8..11}, * s1, coalesced store ----
        radix64(w);
        float* __restrict__ orow = out + (size_t)row * D_DIM;
#pragma unroll
        for (int r = 0; r < 16; ++r) {
            const int off = (r << 8) + l4;
            const float4 sv = *reinterpret_cast<const float4*>(s1 + off);
            const v2f o0 = pkmul(w[2 * r],     (v2f){sv.x, sv.y});
            const v2f o1 = pkmul(w[2 * r + 1], (v2f){sv.z, sv.w});
            *reinterpret_cast<float4*>(orow + off) = make_float4(o0.x, o0.y, o1.x, o1.y);
        }
    }
}

extern "C" void kernel_launch(void* const* d_in, const int* in_sizes, int n_in,
                              void* d_out, int out_size, void* d_ws, size_t ws_size,
                              hipStream_t stream) {
    const float* x     = (const float*)d_in[0];
    const float* s1    = (const float*)d_in[1];
    const float* s2    = (const float*)d_in[2];
    const float* g_mu  = (const float*)d_in[3];
    const float* g_rho = (const float*)d_in[4];
    const float* eps   = (const float*)d_in[5];
    // d_in[6] = H : realized implicitly by the FWHT butterflies.

    float* u_perm = (float*)d_ws;
    float* out    = (float*)d_out;

    const int N = in_sizes[0] / D_DIM;

    compute_u_kernel<<<(D_DIM + 255) / 256, 256, 0, stream>>>(g_mu, g_rho, eps, u_perm);
    whvi_kernel<<<NWG, 256, 0, stream>>>(x, s1, s2, u_perm, out, N);
}

// Round 10
// 188.471 us; speedup vs baseline: 4.1265x; 4.1265x over previous
//
#include <hip/hip_runtime.h>
#include <math.h>

#define D_DIM 4096
#define NWG 1280  // 5 WGs/CU x 256 CUs, persistent grid-stride

typedef float v2f __attribute__((ext_vector_type(2)));

// ---- packed-f32 butterfly primitives (VOP3P) ----
__device__ __forceinline__ v2f bfly0(v2f a) {
    v2f d;
    asm("v_pk_add_f32 %0, %1, %2 op_sel:[0,1] op_sel_hi:[0,1] neg_hi:[0,1]"
        : "=v"(d) : "v"(a), "v"(a));
    return d;
}
__device__ __forceinline__ v2f pkadd(v2f a, v2f b) {
    v2f d; asm("v_pk_add_f32 %0, %1, %2" : "=v"(d) : "v"(a), "v"(b)); return d;
}
__device__ __forceinline__ v2f pksub(v2f a, v2f b) {
    v2f d; asm("v_pk_add_f32 %0, %1, %2 neg_lo:[0,1] neg_hi:[0,1]" : "=v"(d) : "v"(a), "v"(b)); return d;
}
__device__ __forceinline__ v2f pkmul(v2f a, v2f b) {
    v2f d; asm("v_pk_mul_f32 %0, %1, %2" : "=v"(d) : "v"(a), "v"(b)); return d;
}

// In-register FWHT over 4 bits: 16 values as 8 packed v2f (verified round 2).
__device__ __forceinline__ void radix16(v2f w[8]) {
#pragma unroll
    for (int p = 0; p < 8; ++p) w[p] = bfly0(w[p]);
#pragma unroll
    for (int s = 0; s < 3; ++s) {
        const int d = 1 << s;
#pragma unroll
        for (int p = 0; p < 8; ++p) {
            if (!(p & d)) {
                const v2f a = w[p];
                const v2f b = w[p + d];
                w[p]     = pkadd(a, b);
                w[p + d] = pksub(a, b);
            }
        }
    }
}

// async global->LDS, 16 B per lane; LDS dest = wave-uniform base + lane*16.
__device__ __forceinline__ void gload_lds16(const float* g, float* lp) {
    __builtin_amdgcn_global_load_lds(
        (const __attribute__((address_space(1))) void*)g,
        (__attribute__((address_space(3))) void*)lp, 16, 0, 0);
}

// Phase barrier: drain DS ops only (NOT vmcnt -> glds prefetch stays in
// flight across barriers; __syncthreads would emit vmcnt(0) and kill it).
__device__ __forceinline__ void phase_barrier() {
    asm volatile("s_waitcnt lgkmcnt(0)" ::: "memory");
    __builtin_amdgcn_s_barrier();
    __builtin_amdgcn_sched_barrier(0);
}

// transpose-buffer swizzle: fold e-bits 8,9 into bank bits 4,2.
// Involution/bijection; bits 0-1 untouched (b128 contiguity+alignment kept).
// Banks: phases A/B/D/E = 2-way (free); phase C b128 = BW-floor.
__device__ __forceinline__ int swzW(int e) {
    return e ^ (((e >> 8) & 1) << 4) ^ (((e >> 9) & 1) << 2);
}

// u in NATURAL order, 1/64 FWHT normalization folded in.
__global__ void compute_u_kernel(const float* __restrict__ g_mu,
                                 const float* __restrict__ g_rho,
                                 const float* __restrict__ eps,
                                 float* __restrict__ u) {
    const int i = blockIdx.x * blockDim.x + threadIdx.x;
    if (i < D_DIM) {
        const float r = g_rho[i];
        const float sp = (r > 20.0f) ? r : log1pf(expf(r));
        u[i] = (g_mu[i] + sp * eps[i]) * 0.015625f;
    }
}

// Persistent cooperative kernel. Per WG: 256 threads work on one row at a
// time; stage buffer (16 KB, linear, glds dest) double-dutied with a
// transpose buffer (16 KB, swizzled). 5 phases per row (verified round-2
// dataflow): A: bits 8-11 (read stage * S2) -> trb; B: bits 4-7 in-place;
// C: bits 0-3, *U, bits 0-3 (b128); D: bits 4-7; E: bits 8-11, *S1, store.
// vmcnt algebra per row: [glds_{r+1}(4/wave)] ... [stores_r(16/wave)];
// bottom s_waitcnt vmcnt(16) retires exactly glds_{r+1} (+older stores).
__global__ __launch_bounds__(256, 5) void whvi_kernel(const float* __restrict__ x,
                                                      const float* __restrict__ s1,
                                                      const float* __restrict__ s2,
                                                      const float* __restrict__ u,
                                                      float* __restrict__ out,
                                                      int nrows) {
    __shared__ float stg[D_DIM];  // x stage: linear (glds destination)
    __shared__ float trb[D_DIM];  // transpose buffer: swzW layout
    const int tid = threadIdx.x;
    const int wv = tid >> 6;
    const int l6 = tid & 63;

    // ---- persistent scale registers ----
    float S2r[16], S1r[16];
#pragma unroll
    for (int m = 0; m < 16; ++m) {
        S2r[m] = s2[tid + (m << 8)];
        S1r[m] = s1[tid + (m << 8)];
    }
    float4 U4[4];
#pragma unroll
    for (int c = 0; c < 4; ++c)
        U4[c] = *reinterpret_cast<const float4*>(u + (tid << 4) + (c << 2));

    // ---- prologue: glds row0 into stage, drain, barrier ----
    int row = blockIdx.x;
    if (row < nrows) {
        const float* xr = x + (size_t)row * D_DIM;
#pragma unroll
        for (int k = 0; k < 4; ++k)
            gload_lds16(xr + (k << 10) + (wv << 8) + (l6 << 2),
                        &stg[(k << 10) + (wv << 8)]);
    }
    asm volatile("s_waitcnt vmcnt(0)" ::: "memory");
    __builtin_amdgcn_s_barrier();
    __builtin_amdgcn_sched_barrier(0);

    for (; row < nrows; row += NWG) {
        const int next = row + NWG;
        v2f w[8];

        // ---- Phase A: read stage (linear), *s2, FWHT bits 8-11, write trb ----
#pragma unroll
        for (int m = 0; m < 16; ++m) {
            const float val = stg[tid + (m << 8)] * S2r[m];
            if (m & 1) w[m >> 1].y = val; else w[m >> 1].x = val;
        }
        radix16(w);
#pragma unroll
        for (int m = 0; m < 16; ++m)
            trb[swzW(tid + (m << 8))] = (m & 1) ? w[m >> 1].y : w[m >> 1].x;
        phase_barrier();  // also guarantees all waves done READING stg

        // ---- prefetch next row into stage (stays in flight all row) ----
        if (next < nrows) {
            const float* xn = x + (size_t)next * D_DIM;
#pragma unroll
            for (int k = 0; k < 4; ++k)
                gload_lds16(xn + (k << 10) + (wv << 8) + (l6 << 2),
                            &stg[(k << 10) + (wv << 8)]);
        }
        __builtin_amdgcn_sched_barrier(0);

        // ---- Phase B: FWHT bits 4-7, in place ----
        {
            const int base = ((tid >> 4) << 8) | (tid & 15);
#pragma unroll
            for (int m = 0; m < 16; ++m) {
                const float val = trb[swzW(base | (m << 4))];
                if (m & 1) w[m >> 1].y = val; else w[m >> 1].x = val;
            }
            radix16(w);
#pragma unroll
            for (int m = 0; m < 16; ++m)
                trb[swzW(base | (m << 4))] = (m & 1) ? w[m >> 1].y : w[m >> 1].x;
        }
        phase_barrier();

        // ---- Phase C: FWHT bits 0-3, *u, FWHT bits 0-3 (b128, in place) ----
        {
            const int cb = tid << 4;
#pragma unroll
            for (int c = 0; c < 4; ++c) {
                const float4 f = *reinterpret_cast<const float4*>(&trb[swzW(cb | (c << 2))]);
                w[2 * c]     = (v2f){f.x, f.y};
                w[2 * c + 1] = (v2f){f.z, f.w};
            }
            radix16(w);
#pragma unroll
            for (int c = 0; c < 4; ++c) {
                w[2 * c]     = pkmul(w[2 * c],     (v2f){U4[c].x, U4[c].y});
                w[2 * c + 1] = pkmul(w[2 * c + 1], (v2f){U4[c].z, U4[c].w});
            }
            radix16(w);
#pragma unroll
            for (int c = 0; c < 4; ++c) {
                const float4 f = make_float4(w[2 * c].x, w[2 * c].y,
                                             w[2 * c + 1].x, w[2 * c + 1].y);
                *reinterpret_cast<float4*>(&trb[swzW(cb | (c << 2))]) = f;
            }
        }
        phase_barrier();

        // ---- Phase D: FWHT bits 4-7, in place ----
        {
            const int base = ((tid >> 4) << 8) | (tid & 15);
#pragma unroll
            for (int m = 0; m < 16; ++m) {
                const float val = trb[swzW(base | (m << 4))];
                if (m & 1) w[m >> 1].y = val; else w[m >> 1].x = val;
            }
            radix16(w);
#pragma unroll
            for (int m = 0; m < 16; ++m)
                trb[swzW(base | (m << 4))] = (m & 1) ? w[m >> 1].y : w[m >> 1].x;
        }
        phase_barrier();

        // ---- Phase E: FWHT bits 8-11, *s1, coalesced b32 stores ----
#pragma unroll
        for (int m = 0; m < 16; ++m) {
            const float val = trb[swzW(tid + (m << 8))];
            if (m & 1) w[m >> 1].y = val; else w[m >> 1].x = val;
        }
        radix16(w);
        float* orow = out + (size_t)row * D_DIM;
#pragma unroll
        for (int m = 0; m < 16; ++m) {
            const float val = (m & 1) ? w[m >> 1].y : w[m >> 1].x;
            orow[tid + (m << 8)] = val * S1r[m];
        }

        // ---- bottom: retire exactly the glds (keep stores in flight),
        //      then barrier (trb reuse by next A + stage readiness) ----
        asm volatile("s_waitcnt vmcnt(16)" ::: "memory");
        asm volatile("s_waitcnt lgkmcnt(0)" ::: "memory");
        __builtin_amdgcn_s_barrier();
        __builtin_amdgcn_sched_barrier(0);
    }
}

extern "C" void kernel_launch(void* const* d_in, const int* in_sizes, int n_in,
                              void* d_out, int out_size, void* d_ws, size_t ws_size,
                              hipStream_t stream) {
    const float* x     = (const float*)d_in[0];
    const float* s1    = (const float*)d_in[1];
    const float* s2    = (const float*)d_in[2];
    const float* g_mu  = (const float*)d_in[3];
    const float* g_rho = (const float*)d_in[4];
    const float* eps   = (const float*)d_in[5];
    // d_in[6] = H : realized implicitly by the FWHT butterflies.

    float* u   = (float*)d_ws;
    float* out = (float*)d_out;

    const int N = in_sizes[0] / D_DIM;

    compute_u_kernel<<<(D_DIM + 255) / 256, 256, 0, stream>>>(g_mu, g_rho, eps, u);
    whvi_kernel<<<NWG, 256, 0, stream>>>(x, s1, s2, u, out, N);
}

// Round 11
// 112.320 us; speedup vs baseline: 6.9242x; 1.6780x over previous
//
#include <hip/hip_runtime.h>
#include <math.h>

#define D_DIM 4096
#define NWG 1024  // 4 WGs/CU x 256 CUs, persistent grid-stride (16 rows/WG)

typedef float v2f __attribute__((ext_vector_type(2)));

// ---- packed-f32 butterfly primitives (VOP3P) ----
__device__ __forceinline__ v2f bfly0(v2f a) {
    v2f d;
    asm("v_pk_add_f32 %0, %1, %2 op_sel:[0,1] op_sel_hi:[0,1] neg_hi:[0,1]"
        : "=v"(d) : "v"(a), "v"(a));
    return d;
}
__device__ __forceinline__ v2f pkadd(v2f a, v2f b) {
    v2f d; asm("v_pk_add_f32 %0, %1, %2" : "=v"(d) : "v"(a), "v"(b)); return d;
}
__device__ __forceinline__ v2f pksub(v2f a, v2f b) {
    v2f d; asm("v_pk_add_f32 %0, %1, %2 neg_lo:[0,1] neg_hi:[0,1]" : "=v"(d) : "v"(a), "v"(b)); return d;
}
__device__ __forceinline__ v2f pkmul(v2f a, v2f b) {
    v2f d; asm("v_pk_mul_f32 %0, %1, %2" : "=v"(d) : "v"(a), "v"(b)); return d;
}

// In-register FWHT over 4 bits: 16 values as 8 packed v2f.
__device__ __forceinline__ void radix16(v2f w[8]) {
#pragma unroll
    for (int p = 0; p < 8; ++p) w[p] = bfly0(w[p]);
#pragma unroll
    for (int s = 0; s < 3; ++s) {
        const int d = 1 << s;
#pragma unroll
        for (int p = 0; p < 8; ++p) {
            if (!(p & d)) {
                const v2f a = w[p];
                const v2f b = w[p + d];
                w[p]     = pkadd(a, b);
                w[p + d] = pksub(a, b);
            }
        }
    }
}

// async global->LDS, 16 B per lane; LDS dest = wave-uniform base + lane*16.
__device__ __forceinline__ void gload_lds16(const float* g, float* lp) {
    __builtin_amdgcn_global_load_lds(
        (const __attribute__((address_space(1))) void*)g,
        (__attribute__((address_space(3))) void*)lp, 16, 0, 0);
}

// Phase barrier: drain DS ops only (NOT vmcnt -> glds prefetch stays in
// flight across barriers; __syncthreads would emit vmcnt(0) and kill it).
__device__ __forceinline__ void phase_barrier() {
    asm volatile("s_waitcnt lgkmcnt(0)" ::: "memory");
    __builtin_amdgcn_s_barrier();
    __builtin_amdgcn_sched_barrier(0);
}

// Rank-complete transpose-buffer swizzle (re-derived per access pattern):
//   b4 ^= e8 ^ e5 ;  b3 ^= e7 ;  b2 ^= e9 ^ e6
// - Phase A/E (e = m<<8 | tid):      bank = (l4^l5^m0, l3^W1, l2^m1^W0, l1, l0) -> 2-way (free)
// - Phase B/D (e = t74<<8|m<<4|t30): bank = (m0^l4^m1, l3^m3, l2^l5^m2, l1, l0) -> 2-way (free)
// - Phase C   (e = tid<<4|c<<2|j):   quad = (l0^l4^l1, l3^c1, l5^l2^c0) -> 8 lanes/quad
//                                    = exactly the 256-word/32-bank floor for b128
// Triangular XOR (high bits into low) -> bijective involution; bits 1:0
// untouched -> b128 contiguity + 16B alignment preserved.
__device__ __forceinline__ int swzW(int e) {
    const int x4 = ((e >> 8) ^ (e >> 5)) & 1;
    const int x3 = (e >> 7) & 1;
    const int x2 = ((e >> 9) ^ (e >> 6)) & 1;
    return e ^ (x4 << 4) ^ (x3 << 3) ^ (x2 << 2);
}

// u in NATURAL order, 1/64 FWHT normalization folded in.
__global__ void compute_u_kernel(const float* __restrict__ g_mu,
                                 const float* __restrict__ g_rho,
                                 const float* __restrict__ eps,
                                 float* __restrict__ u) {
    const int i = blockIdx.x * blockDim.x + threadIdx.x;
    if (i < D_DIM) {
        const float r = g_rho[i];
        const float sp = (r > 20.0f) ? r : log1pf(expf(r));
        u[i] = (g_mu[i] + sp * eps[i]) * 0.015625f;
    }
}

// Persistent cooperative kernel (round-10 structure, spill-free + clean banks).
// 256 threads/row; stage buffer (16 KB, linear glds dest) + transpose buffer
// (16 KB, swzW). Phases per row: A: *s2, bits 8-11 (stage->trb); B: bits 4-7;
// C: bits 0-3, *u, bits 0-3 (b128); D: bits 4-7; E: bits 8-11, *s1, store.
// Per-wave vmem queue at bottom (oldest->newest): 4 glds, 16 stores;
// s_waitcnt vmcnt(16) retires exactly the glds, keeps stores in flight.
__global__ __launch_bounds__(256, 4) void whvi_kernel(const float* __restrict__ x,
                                                      const float* __restrict__ s1,
                                                      const float* __restrict__ s2,
                                                      const float* __restrict__ u,
                                                      float* __restrict__ out,
                                                      int nrows) {
    __shared__ float stg[D_DIM];  // x stage: linear (glds destination)
    __shared__ float trb[D_DIM];  // transpose buffer: swzW layout
    const int tid = threadIdx.x;
    const int wv = tid >> 6;
    const int l6 = tid & 63;

    // ---- persistent scale registers (fits: ~110 live < 128 VGPR cap) ----
    float S2r[16], S1r[16];
#pragma unroll
    for (int m = 0; m < 16; ++m) {
        S2r[m] = s2[tid + (m << 8)];
        S1r[m] = s1[tid + (m << 8)];
    }
    float4 U4[4];
#pragma unroll
    for (int c = 0; c < 4; ++c)
        U4[c] = *reinterpret_cast<const float4*>(u + (tid << 4) + (c << 2));

    // ---- prologue: glds row0 into stage, drain, barrier ----
    int row = blockIdx.x;
    if (row < nrows) {
        const float* xr = x + (size_t)row * D_DIM;
#pragma unroll
        for (int k = 0; k < 4; ++k)
            gload_lds16(xr + (k << 10) + (wv << 8) + (l6 << 2),
                        &stg[(k << 10) + (wv << 8)]);
    }
    asm volatile("s_waitcnt vmcnt(0)" ::: "memory");
    __builtin_amdgcn_s_barrier();
    __builtin_amdgcn_sched_barrier(0);

    for (; row < nrows; row += NWG) {
        const int next = row + NWG;
        v2f w[8];

        // ---- Phase A: read stage (linear), *s2, FWHT bits 8-11, write trb ----
#pragma unroll
        for (int m = 0; m < 16; ++m) {
            const float val = stg[tid + (m << 8)] * S2r[m];
            if (m & 1) w[m >> 1].y = val; else w[m >> 1].x = val;
        }
        radix16(w);
#pragma unroll
        for (int m = 0; m < 16; ++m)
            trb[swzW(tid + (m << 8))] = (m & 1) ? w[m >> 1].y : w[m >> 1].x;
        phase_barrier();  // also: all waves done READING stg

        // ---- prefetch next row into stage (stays in flight all row) ----
        if (next < nrows) {
            const float* xn = x + (size_t)next * D_DIM;
#pragma unroll
            for (int k = 0; k < 4; ++k)
                gload_lds16(xn + (k << 10) + (wv << 8) + (l6 << 2),
                            &stg[(k << 10) + (wv << 8)]);
        }
        __builtin_amdgcn_sched_barrier(0);

        // ---- Phase B: FWHT bits 4-7, in place ----
        {
            const int base = ((tid >> 4) << 8) | (tid & 15);
#pragma unroll
            for (int m = 0; m < 16; ++m) {
                const float val = trb[swzW(base | (m << 4))];
                if (m & 1) w[m >> 1].y = val; else w[m >> 1].x = val;
            }
            radix16(w);
#pragma unroll
            for (int m = 0; m < 16; ++m)
                trb[swzW(base | (m << 4))] = (m & 1) ? w[m >> 1].y : w[m >> 1].x;
        }
        phase_barrier();

        // ---- Phase C: FWHT bits 0-3, *u, FWHT bits 0-3 (b128, in place) ----
        {
            const int cb = tid << 4;
#pragma unroll
            for (int c = 0; c < 4; ++c) {
                const float4 f = *reinterpret_cast<const float4*>(&trb[swzW(cb | (c << 2))]);
                w[2 * c]     = (v2f){f.x, f.y};
                w[2 * c + 1] = (v2f){f.z, f.w};
            }
            radix16(w);
#pragma unroll
            for (int c = 0; c < 4; ++c) {
                w[2 * c]     = pkmul(w[2 * c],     (v2f){U4[c].x, U4[c].y});
                w[2 * c + 1] = pkmul(w[2 * c + 1], (v2f){U4[c].z, U4[c].w});
            }
            radix16(w);
#pragma unroll
            for (int c = 0; c < 4; ++c) {
                const float4 f = make_float4(w[2 * c].x, w[2 * c].y,
                                             w[2 * c + 1].x, w[2 * c + 1].y);
                *reinterpret_cast<float4*>(&trb[swzW(cb | (c << 2))]) = f;
            }
        }
        phase_barrier();

        // ---- Phase D: FWHT bits 4-7, in place ----
        {
            const int base = ((tid >> 4) << 8) | (tid & 15);
#pragma unroll
            for (int m = 0; m < 16; ++m) {
                const float val = trb[swzW(base | (m << 4))];
                if (m & 1) w[m >> 1].y = val; else w[m >> 1].x = val;
            }
            radix16(w);
#pragma unroll
            for (int m = 0; m < 16; ++m)
                trb[swzW(base | (m << 4))] = (m & 1) ? w[m >> 1].y : w[m >> 1].x;
        }
        phase_barrier();

        // ---- Phase E: FWHT bits 8-11, *s1, coalesced b32 stores ----
#pragma unroll
        for (int m = 0; m < 16; ++m) {
            const float val = trb[swzW(tid + (m << 8))];
            if (m & 1) w[m >> 1].y = val; else w[m >> 1].x = val;
        }
        radix16(w);
        float* orow = out + (size_t)row * D_DIM;
#pragma unroll
        for (int m = 0; m < 16; ++m) {
            const float val = (m & 1) ? w[m >> 1].y : w[m >> 1].x;
            orow[tid + (m << 8)] = val * S1r[m];
        }

        // ---- bottom: retire exactly the glds (keep stores in flight),
        //      then barrier (trb reuse by next A + stage readiness) ----
        asm volatile("s_waitcnt vmcnt(16)" ::: "memory");
        asm volatile("s_waitcnt lgkmcnt(0)" ::: "memory");
        __builtin_amdgcn_s_barrier();
        __builtin_amdgcn_sched_barrier(0);
    }
}

extern "C" void kernel_launch(void* const* d_in, const int* in_sizes, int n_in,
                              void* d_out, int out_size, void* d_ws, size_t ws_size,
                              hipStream_t stream) {
    const float* x     = (const float*)d_in[0];
    const float* s1    = (const float*)d_in[1];
    const float* s2    = (const float*)d_in[2];
    const float* g_mu  = (const float*)d_in[3];
    const float* g_rho = (const float*)d_in[4];
    const float* eps   = (const float*)d_in[5];
    // d_in[6] = H : realized implicitly by the FWHT butterflies.

    float* u   = (float*)d_ws;
    float* out = (float*)d_out;

    const int N = in_sizes[0] / D_DIM;

    compute_u_kernel<<<(D_DIM + 255) / 256, 256, 0, stream>>>(g_mu, g_rho, eps, u);
    whvi_kernel<<<NWG, 256, 0, stream>>>(x, s1, s2, u, out, N);
}